// Round 10
// baseline (564.512 us; speedup 1.0000x reference)
//
#include <hip/hip_runtime.h>
#include <hip/hip_bf16.h>
#include <math.h>

#define NB 4096
#define SE 8
#define ND 64      // DICT
#define C1 64
#define C2 128
#define NE 256
#define NZ 1024
#define CHUNK 2048
#define KACT 8192
#define KSPLIT 8
#define C1PAD 968  // cb-stride in shorts: 1936B == bank offset 4 (breaks 4-way aliasing)

#define W1M_N (3*12*64*8)        // 18432 (bf16 hi/lo, conv1 layout [j][o][c], j padded to 12)
#define W2M_N (3*18*128*32)      // 221184 (bf16 hi/lo, conv2 layout [j*2+h2][och][32])
#define ZT_N  (256*1024)
#define PREP_TOTAL (W1M_N + W2M_N + ZT_N)       // 501760
#define PREP_TOTAL2 (PREP_TOTAL + 512)          // +wnorm = 502272 = 1962*256
#define LW_N (NE*KACT)                          // 2097152 per phi

typedef __attribute__((ext_vector_type(8))) short bf16x8;
typedef __attribute__((ext_vector_type(4))) float f32x4;
typedef __attribute__((ext_vector_type(8))) unsigned short u16x8;
typedef __attribute__((ext_vector_type(4))) unsigned short u16x4;

static __device__ __forceinline__ unsigned short f2bf(float v) {
  __hip_bfloat16 h = __float2bfloat16(v);
  return __builtin_bit_cast(unsigned short, h);
}
static __device__ __forceinline__ float bf2f(unsigned short u) {
  return __bfloat162float(__builtin_bit_cast(__hip_bfloat16, u));
}

// ---------------- prep: w1 -> [j][o][c] bf16 hi/lo (j padded 9->12),
//     w2 -> [j*2+h2][och][32] bf16 hi/lo (coalesced per-step),
//     zT transpose, wnorm = max_norm-renormalized embedding table ----------------
__global__ __launch_bounds__(256) void prep_kernel(
    const float* __restrict__ w1_0, const float* __restrict__ w1_1, const float* __restrict__ w1_2,
    const float* __restrict__ w2_0, const float* __restrict__ w2_1, const float* __restrict__ w2_2,
    const float* __restrict__ z, const float* __restrict__ w_embed,
    unsigned short* __restrict__ w1mh, unsigned short* __restrict__ w1ml,
    unsigned short* __restrict__ w2mh, unsigned short* __restrict__ w2ml,
    float* __restrict__ zT, float* __restrict__ wnorm)
{
  int idx = blockIdx.x * 256 + threadIdx.x;
  if (idx < W1M_N) {
    int p = idx / 6144; int r = idx - p*6144;
    int j = r >> 9; int rem = r & 511; int o = rem >> 3; int c = rem & 7;
    const float* w1 = (p == 0) ? w1_0 : (p == 1) ? w1_1 : w1_2;
    // src layout [o][c][ky][kx]; dst [j][o*8 + c], j = ky*3+kx, j>=9 zero-padded
    float v = (j < 9) ? w1[o*72 + c*9 + j] : 0.f;
    unsigned short h = f2bf(v);
    w1mh[idx] = h;
    w1ml[idx] = f2bf(v - bf2f(h));
  } else if (idx < W1M_N + W2M_N) {
    int r0 = idx - W1M_N;
    int p = r0 / (128*576); int r = r0 - p*(128*576);
    int o = r / 576; int rem = r - o*576; int j = rem >> 6; int c = rem & 63;
    const float* w2 = (p == 0) ? w2_0 : (p == 1) ? w2_1 : w2_2;
    // w2 src [o][c][ky][kx] -> dst [p][(j*2 + c/32)*4096 + o*32 + (c%32)]
    float v = w2[o*576 + c*9 + j];
    unsigned short h = f2bf(v);
    const int d = p*(128*576) + ((j << 1) + (c >> 5))*4096 + o*32 + (c & 31);
    w2mh[d] = h;
    w2ml[d] = f2bf(v - bf2f(h));
  } else if (idx < PREP_TOTAL) {
    int r = idx - (W1M_N + W2M_N);
    int e = r >> 10, n = r & 1023;
    zT[r] = z[n*256 + e];   // zT[e][n]
  } else if (idx < PREP_TOTAL2) {
    int t = idx - PREP_TOTAL;           // 512 threads: o = t>>3, c = t&7
    int o = t >> 3, c = t & 7;
    float ss = 0.f;
    #pragma unroll
    for (int e = 0; e < 8; ++e) { float u = w_embed[o*8 + e]; ss += u*u; }
    float nrm = sqrtf(ss);
    float sc = fminf(1.f, 1.f / fmaxf(nrm, 1e-7f));
    wnorm[o*8 + c] = w_embed[o*8 + c] * sc;
  }
}

// ---------------- per-phi: lw -> bf16 hi (+ lo), and prefill outvec with bias ------
__global__ __launch_bounds__(256) void prep_lw_kernel(
    const float* __restrict__ lw, unsigned short* __restrict__ lwh,
    unsigned short* __restrict__ lwl, int do_lo,
    float* __restrict__ outvec, const float* __restrict__ lb)
{
  int idx = blockIdx.x * 256 + threadIdx.x;
  float v = lw[idx];
  unsigned short h = f2bf(v);
  lwh[idx] = h;
  if (do_lo) lwl[idx] = f2bf(v - bf2f(h));
  if (idx < NB*NE) outvec[idx] = lb[idx & (NE-1)];   // bias prefill for atomic GEMM
}

// ---------------- fused embed + conv1(16x16 bf16x3 MFMA) + conv2(16x16 bf16 MFMA) ----
// 256 threads = 4 waves, 1 image/block, ~34.9KB LDS -> 4 blocks/CU (16 waves/CU).
// Embed: no LDS table -- pixels gather 32B rows of prep'd wnorm (global, L1-hot).
// c1 LDS cb-major c1[cb][lin][sub] with cb-stride C1PAD=968 shorts (bank +4/cb):
// conv2 b128 A-reads now bank-staggered across lk4 groups (was 4-way aliased).
// conv1 swapped 16x16: A=w1[out][k], B=x[k][px]; wave = 16-px quarter, 64 out-ch.
// conv2 (R6 decomposition -- empirical optimum): wave wid -> och [wid*32,+32),
//   all 64 px (mf=4, nf=2): B-loads 2/step/wave (1KB contiguous, L1-hot),
//   A 8 ds_reads/step feeding 16 MFMAs, 8 independent acc chains.
// PASSES: 2 = Ah.Bh + Al.Bh ; 3 = + Ah.Bl. conv1 always 3-pass.
template<int PASSES>
__global__ __launch_bounds__(256, 4) void conv_phi_kernel(
    const int* __restrict__ s, const int* __restrict__ sp,
    const float* __restrict__ wnorm,
    const unsigned short* __restrict__ w1mh, const unsigned short* __restrict__ w1ml,
    const float* __restrict__ b1,
    const unsigned short* __restrict__ w2mh, const unsigned short* __restrict__ w2ml,
    const float* __restrict__ b2,
    unsigned short* __restrict__ acth, unsigned short* __restrict__ actl,
    int mode, int b_start)
{
  __shared__ __align__(16) unsigned short xph[960];        // [10][12][8] NHWC hi
  __shared__ __align__(16) unsigned short xpl[960];        // [10][12][8] NHWC lo
  __shared__ __align__(16) unsigned short c1h[8*C1PAD];    // [8 cb][120 lin][8 sub] padded
  __shared__ __align__(16) unsigned short c1l[8*C1PAD];

  const int tid = threadIdx.x;
  const int b = b_start + blockIdx.x;

  {
    int4 z4 = {0,0,0,0};
    for (int t = tid; t < 120; t += 256) { ((int4*)xph)[t] = z4; ((int4*)xpl)[t] = z4; }
    for (int t = tid; t < C1PAD; t += 256) { ((int4*)c1h)[t] = z4; ((int4*)c1l)[t] = z4; }
  }
  __syncthreads();

  // build padded input tile: one pixel per thread, gather 32B wnorm rows from L1
  if (tid < 64) {
    const int si  = s[b*64 + tid];
    const int spi = sp[b*64 + tid];
    const float4 a0 = *(const float4*)(wnorm + si*8);
    const float4 a1v = *(const float4*)(wnorm + si*8 + 4);
    const float4 c0 = *(const float4*)(wnorm + spi*8);
    const float4 c1v = *(const float4*)(wnorm + spi*8 + 4);
    float e0[8] = {a0.x,a0.y,a0.z,a0.w, a1v.x,a1v.y,a1v.z,a1v.w};
    float e1[8] = {c0.x,c0.y,c0.z,c0.w, c1v.x,c1v.y,c1v.z,c1v.w};
    u16x8 hv, lv;
    #pragma unroll
    for (int c = 0; c < SE; ++c) {
      float v = (mode == 0) ? e0[c] : (mode == 1) ? (e1[c] - e0[c]) : e1[c];
      unsigned short h = f2bf(v);
      hv[c] = h;
      lv[c] = f2bf(v - bf2f(h));
    }
    const int lin = ((tid >> 3) + 1)*12 + (tid & 7) + 1;
    *(u16x8*)(xph + lin*8) = hv;
    *(u16x8*)(xpl + lin*8) = lv;
  }
  __syncthreads();

  // ---- conv1 via 16x16 MFMA (swapped): A=w1[out][k], B=x[k][pixel] ----
  {
    const int lane = tid & 63, wid = tid >> 6;
    const int ph = wid;
    const int l15 = lane & 15, lk4 = lane >> 4;

    f32x4 a1[4];
    #pragma unroll
    for (int fm = 0; fm < 4; ++fm) a1[fm] = (f32x4){0.f,0.f,0.f,0.f};

    #pragma unroll
    for (int kk = 0; kk < 3; ++kk) {
      const int j = (kk << 2) + lk4;          // 0..11; j>=9 rows are zero in w1m
      const int jc = (j > 8) ? 8 : j;         // clamp X read in-bounds (W=0 kills it)
      const int dy = jc / 3, dx = jc - 3*(jc/3);
      bf16x8 Wh[4], Wl[4];
      #pragma unroll
      for (int fm = 0; fm < 4; ++fm) {
        const int o = (fm << 4) + l15;
        Wh[fm] = *(const bf16x8*)(w1mh + (j << 9) + (o << 3));
        Wl[fm] = *(const bf16x8*)(w1ml + (j << 9) + (o << 3));
      }
      const int p = (ph << 4) + l15;
      const int lin = ((p >> 3) + dy)*12 + (p & 7) + dx;
      const bf16x8 Xh = *(const bf16x8*)(xph + (lin << 3));
      const bf16x8 Xl = *(const bf16x8*)(xpl + (lin << 3));
      __builtin_amdgcn_s_setprio(1);
      #pragma unroll
      for (int fm = 0; fm < 4; ++fm) {
        a1[fm] = __builtin_amdgcn_mfma_f32_16x16x32_bf16(Wh[fm], Xh, a1[fm], 0, 0, 0);
        a1[fm] = __builtin_amdgcn_mfma_f32_16x16x32_bf16(Wl[fm], Xh, a1[fm], 0, 0, 0);
        a1[fm] = __builtin_amdgcn_mfma_f32_16x16x32_bf16(Wh[fm], Xl, a1[fm], 0, 0, 0);
      }
      __builtin_amdgcn_s_setprio(0);
    }

    // c1 write (cb-major, padded): lane holds out-ch obase..+3 of pixel p
    const int p = (ph << 4) + l15;
    const int lin = ((p >> 3) + 1)*12 + (p & 7) + 1;
    #pragma unroll
    for (int fm = 0; fm < 4; ++fm) {
      const int obase = (fm << 4) + (lk4 << 2);
      const float4 bv = *(const float4*)(b1 + obase);
      const int idx2 = (obase >> 3)*C1PAD + lin*8 + (obase & 7);
      u16x4 hv, lv;
      {
        float v0 = fmaxf(a1[fm][0] + bv.x, 0.f);
        float v1 = fmaxf(a1[fm][1] + bv.y, 0.f);
        float v2 = fmaxf(a1[fm][2] + bv.z, 0.f);
        float v3 = fmaxf(a1[fm][3] + bv.w, 0.f);
        hv[0] = f2bf(v0); hv[1] = f2bf(v1); hv[2] = f2bf(v2); hv[3] = f2bf(v3);
        lv[0] = f2bf(v0 - bf2f(hv[0])); lv[1] = f2bf(v1 - bf2f(hv[1]));
        lv[2] = f2bf(v2 - bf2f(hv[2])); lv[3] = f2bf(v3 - bf2f(hv[3]));
      }
      *(u16x4*)(c1h + idx2) = hv;
      *(u16x4*)(c1l + idx2) = lv;
    }
  }
  __syncthreads();

  // ---- conv2 MFMA: wave wid -> out-ch [wid*32,+32), M=64 px, K=576, barrier-free ----
  {
    const int lane = tid & 63, wid = tid >> 6;
    const int ob = wid << 5;
    const int l15 = lane & 15, lk4 = lane >> 4;
    const int y0b = l15 >> 3, x0 = l15 & 7;

    f32x4 acc[4][2];
    #pragma unroll
    for (int mf = 0; mf < 4; ++mf)
      #pragma unroll
      for (int nf = 0; nf < 2; ++nf) acc[mf][nf] = (f32x4){0.f,0.f,0.f,0.f};

    #pragma unroll
    for (int j = 0; j < 9; ++j) {
      const int dy = j / 3, dx = j - 3*(j/3);
      #pragma unroll
      for (int h2 = 0; h2 < 2; ++h2) {
        const int sbase = ((j << 1) + h2) << 12;       // step-slice [j*2+h2][128][32]
        bf16x8 Bh[2], Bl[2];
        #pragma unroll
        for (int nf = 0; nf < 2; ++nf) {
          const int orow = ob + (nf << 4) + l15;
          const int a = sbase + orow*32 + (lk4 << 3);  // 1KB contiguous per wave
          Bh[nf] = *(const bf16x8*)(w2mh + a);
          if (PASSES == 3) Bl[nf] = *(const bf16x8*)(w2ml + a);
        }
        const int cbk = (h2 << 2) + lk4;
        bf16x8 Ah[4], Al[4];
        #pragma unroll
        for (int mf = 0; mf < 4; ++mf) {
          const int lin = ((mf << 1) + y0b + dy)*12 + x0 + dx;
          const int a = cbk*C1PAD + (lin << 3);
          Ah[mf] = *(const bf16x8*)(c1h + a);
          Al[mf] = *(const bf16x8*)(c1l + a);
        }
        __builtin_amdgcn_s_setprio(1);
        #pragma unroll
        for (int mf = 0; mf < 4; ++mf) {
          #pragma unroll
          for (int nf = 0; nf < 2; ++nf) {
            acc[mf][nf] = __builtin_amdgcn_mfma_f32_16x16x32_bf16(Ah[mf], Bh[nf], acc[mf][nf], 0, 0, 0);
            acc[mf][nf] = __builtin_amdgcn_mfma_f32_16x16x32_bf16(Al[mf], Bh[nf], acc[mf][nf], 0, 0, 0);
            if (PASSES == 3)
              acc[mf][nf] = __builtin_amdgcn_mfma_f32_16x16x32_bf16(Ah[mf], Bl[nf], acc[mf][nf], 0, 0, 0);
          }
        }
        __builtin_amdgcn_s_setprio(0);
      }
    }

    // store act[img][o*64 + pixel] as bf16 hi (+ lo for PASSES==3)
    const size_t rowbase = (size_t)blockIdx.x * 8192;
    #pragma unroll
    for (int nf = 0; nf < 2; ++nf) {
      const int col = ob + (nf << 4) + l15;
      const float bv = b2[col];
      #pragma unroll
      for (int mf = 0; mf < 4; ++mf) {
        const int p0 = mf*16 + lk4*4;
        u16x4 hv, lv;
        #pragma unroll
        for (int r2 = 0; r2 < 4; ++r2) {
          float v = fmaxf(acc[mf][nf][r2] + bv, 0.f);
          unsigned short hq = f2bf(v);
          hv[r2] = hq;
          lv[r2] = f2bf(v - bf2f(hq));
        }
        *(u16x4*)(acth + rowbase + col*64 + p0) = hv;
        if (PASSES == 3)
          *(u16x4*)(actl + rowbase + col*64 + p0) = lv;
      }
    }
  }
}

// ---------------- LDS-staged bf16 MFMA TN GEMM ----------------
// BM=128, BN=64, BK=64. 256 thr = 4 waves (2x2): wave owns 64x32 = 4x2 frags 16x16.
// A[M][K], B[N][K] bf16 row-major. PASSES: 1 = Ah.Bh ; 3 = Ah.Bh + Ah.Bl + Al.Bh.
// XOR-swizzled LDS (elem col8 ^ ((row&7)<<3)) -> conflict-free ds_read_b128 (T2).
// KC = K/gridDim.z. Epilogue: Cpart != null -> atomicAdd into Cpart (bias prefilled);
// else Cdirect with bias/scale.
template<int PASSES>
__global__ __launch_bounds__(256) void gemm_lds_tn(
    const unsigned short* __restrict__ Ahp, const unsigned short* __restrict__ Alp,
    const unsigned short* __restrict__ Bhp, const unsigned short* __restrict__ Blp,
    int K, float* __restrict__ Cdirect, float* __restrict__ Cpart,
    const float* __restrict__ bias, const float* __restrict__ scale_ptr)
{
  constexpr int NOP = (PASSES == 3) ? 2 : 1;
  __shared__ __align__(16) unsigned short As[NOP][128*64];
  __shared__ __align__(16) unsigned short Bs[NOP][64*64];

  const int tid = threadIdx.x;
  const int lane = tid & 63, wid = tid >> 6;
  const int wm = wid >> 1, wn = wid & 1;
  const int l15 = lane & 15, lk4 = lane >> 4;
  const int M = gridDim.x << 7, N = gridDim.y << 6;
  const int KC = K / gridDim.z;
  const int bm = blockIdx.x << 7, bn = blockIdx.y << 6;
  const int kbase = blockIdx.z * KC;
  const int NT = KC >> 6;

  const int sr = tid >> 3;          // staging row group 0..31
  const int sc8 = (tid & 7) * 8;    // k-elem chunk (16B) within BK=64

  const unsigned short* gA[NOP];
  const unsigned short* gB[NOP];
  gA[0] = Ahp; gB[0] = Bhp;
  if (PASSES == 3) { gA[1] = Alp; gB[1] = Blp; }

  u16x8 ra[NOP][4], rb[NOP][2];

  f32x4 acc[4][2];
  #pragma unroll
  for (int fm = 0; fm < 4; ++fm)
    #pragma unroll
    for (int nf = 0; nf < 2; ++nf) acc[fm][nf] = (f32x4){0.f,0.f,0.f,0.f};

  // prologue: load tile 0 into regs
  {
    const int k0 = kbase + sc8;
    #pragma unroll
    for (int p = 0; p < NOP; ++p) {
      #pragma unroll
      for (int i = 0; i < 4; ++i)
        ra[p][i] = *(const u16x8*)(gA[p] + (size_t)(bm + sr + i*32) * K + k0);
      #pragma unroll
      for (int i = 0; i < 2; ++i)
        rb[p][i] = *(const u16x8*)(gB[p] + (size_t)(bn + sr + i*32) * K + k0);
    }
  }

  for (int t = 0; t < NT; ++t) {
    __syncthreads();                 // LDS consumers of previous tile done
    // swizzled ds_write of staged regs
    #pragma unroll
    for (int p = 0; p < NOP; ++p) {
      #pragma unroll
      for (int i = 0; i < 4; ++i) {
        const int r = sr + i*32;
        *(u16x8*)(&As[p][r*64 + (sc8 ^ ((r & 7) << 3))]) = ra[p][i];
      }
      #pragma unroll
      for (int i = 0; i < 2; ++i) {
        const int r = sr + i*32;
        *(u16x8*)(&Bs[p][r*64 + (sc8 ^ ((r & 7) << 3))]) = rb[p][i];
      }
    }
    __syncthreads();                 // LDS tile ready
    if (t + 1 < NT) {                // issue next tile's global loads early (T14)
      const int k0 = kbase + ((t + 1) << 6) + sc8;
      #pragma unroll
      for (int p = 0; p < NOP; ++p) {
        #pragma unroll
        for (int i = 0; i < 4; ++i)
          ra[p][i] = *(const u16x8*)(gA[p] + (size_t)(bm + sr + i*32) * K + k0);
        #pragma unroll
        for (int i = 0; i < 2; ++i)
          rb[p][i] = *(const u16x8*)(gB[p] + (size_t)(bn + sr + i*32) * K + k0);
      }
    }
    // compute current tile (hides the loads above)
    #pragma unroll
    for (int ks = 0; ks < 2; ++ks) {
      const int kb = ks*32 + lk4*8;
      bf16x8 af[NOP][4], bf[NOP][2];
      #pragma unroll
      for (int p = 0; p < NOP; ++p) {
        #pragma unroll
        for (int fm = 0; fm < 4; ++fm) {
          const int r = wm*64 + fm*16 + l15;
          af[p][fm] = *(const bf16x8*)(&As[p][r*64 + (kb ^ ((r & 7) << 3))]);
        }
        #pragma unroll
        for (int nf = 0; nf < 2; ++nf) {
          const int r = wn*32 + nf*16 + l15;
          bf[p][nf] = *(const bf16x8*)(&Bs[p][r*64 + (kb ^ ((r & 7) << 3))]);
        }
      }
      #pragma unroll
      for (int fm = 0; fm < 4; ++fm) {
        #pragma unroll
        for (int nf = 0; nf < 2; ++nf) {
          acc[fm][nf] = __builtin_amdgcn_mfma_f32_16x16x32_bf16(af[0][fm], bf[0][nf], acc[fm][nf], 0, 0, 0);
          if (PASSES == 3) {
            acc[fm][nf] = __builtin_amdgcn_mfma_f32_16x16x32_bf16(af[0][fm], bf[1][nf], acc[fm][nf], 0, 0, 0);
            acc[fm][nf] = __builtin_amdgcn_mfma_f32_16x16x32_bf16(af[1][fm], bf[0][nf], acc[fm][nf], 0, 0, 0);
          }
        }
      }
    }
  }

  // epilogue: C layout col=l15, row=lk4*4+r2
  if (Cpart) {
    #pragma unroll
    for (int fm = 0; fm < 4; ++fm) {
      #pragma unroll
      for (int nf = 0; nf < 2; ++nf) {
        const int row0 = bm + wm*64 + fm*16 + lk4*4;
        const int col  = bn + wn*32 + nf*16 + l15;
        #pragma unroll
        for (int r2 = 0; r2 < 4; ++r2)
          atomicAdd(Cpart + (size_t)(row0 + r2) * N + col, acc[fm][nf][r2]);
      }
    }
  } else {
    float alpha = scale_ptr ? expf(scale_ptr[0]) : 1.f;
    #pragma unroll
    for (int fm = 0; fm < 4; ++fm) {
      #pragma unroll
      for (int nf = 0; nf < 2; ++nf) {
        const int row0 = bm + wm*64 + fm*16 + lk4*4;
        const int col  = bn + wn*32 + nf*16 + l15;
        const float bv = bias ? bias[col] : 0.f;
        #pragma unroll
        for (int r2 = 0; r2 < 4; ++r2)
          Cdirect[(size_t)(row0 + r2) * N + col] = alpha * acc[fm][nf][r2] + bv;
      }
    }
  }
}

// ---------------- cdist + argmax (farthest code), 8 batch rows per block ----------------
__global__ __launch_bounds__(256) void quant_kernel(
    const float* __restrict__ diff, const float* __restrict__ zT, int* __restrict__ z_ind)
{
  __shared__ __align__(16) float d[8][NE];
  __shared__ float wv[8][4];
  __shared__ int wni[8][4];
  const int tid = threadIdx.x;
  const int b0 = blockIdx.x * 8;
  for (int j = tid; j < 8*NE; j += 256) (&d[0][0])[j] = diff[(size_t)b0*NE + j];
  __syncthreads();

  float zz[4] = {0.f, 0.f, 0.f, 0.f};
  float dot[8][4] = {};
  for (int e = 0; e < NE; e += 4) {
    float4 dd[8];
    #pragma unroll
    for (int r = 0; r < 8; ++r) dd[r] = *(const float4*)(&d[r][e]);
    #pragma unroll
    for (int u = 0; u < 4; ++u) {
      const float* zr = zT + (size_t)(e + u) * NZ + tid;
      float z0 = zr[0], z1 = zr[256], z2 = zr[512], z3 = zr[768];
      zz[0] = fmaf(z0, z0, zz[0]); zz[1] = fmaf(z1, z1, zz[1]);
      zz[2] = fmaf(z2, z2, zz[2]); zz[3] = fmaf(z3, z3, zz[3]);
      #pragma unroll
      for (int r = 0; r < 8; ++r) {
        const float de = (u == 0) ? dd[r].x : (u == 1) ? dd[r].y : (u == 2) ? dd[r].z : dd[r].w;
        dot[r][0] = fmaf(z0, de, dot[r][0]);
        dot[r][1] = fmaf(z1, de, dot[r][1]);
        dot[r][2] = fmaf(z2, de, dot[r][2]);
        dot[r][3] = fmaf(z3, de, dot[r][3]);
      }
    }
  }

  const int lane = tid & 63, wid = tid >> 6;
  #pragma unroll
  for (int r = 0; r < 8; ++r) {
    float best = zz[0] - 2.f*dot[r][0]; int bi = tid;
    float v1 = zz[1] - 2.f*dot[r][1]; if (v1 > best) { best = v1; bi = tid + 256; }
    float v2 = zz[2] - 2.f*dot[r][2]; if (v2 > best) { best = v2; bi = tid + 512; }
    float v3 = zz[3] - 2.f*dot[r][3]; if (v3 > best) { best = v3; bi = tid + 768; }
    for (int m = 1; m < 64; m <<= 1) {
      float ov = __shfl_xor(best, m, 64);
      int   oi = __shfl_xor(bi, m, 64);
      if (ov > best || (ov == best && oi < bi)) { best = ov; bi = oi; }
    }
    if (lane == 0) { wv[r][wid] = best; wni[r][wid] = bi; }
  }
  __syncthreads();
  if (tid < 8) {
    float best = wv[tid][0]; int bi = wni[tid][0];
    #pragma unroll
    for (int w = 1; w < 4; ++w) {
      float v = wv[tid][w]; int n = wni[tid][w];
      if (v > best || (v == best && n < bi)) { best = v; bi = n; }
    }
    z_ind[b0 + tid] = bi;
  }
}

// ---------------- normalize fp32 rows -> bf16 rows ----------------
__global__ __launch_bounds__(256) void norm_to_bf16_kernel(
    const float* __restrict__ v, unsigned short* __restrict__ ob)
{
  const int row = blockIdx.x*4 + (threadIdx.x >> 6);
  const int lane = threadIdx.x & 63;
  float4 x = ((const float4*)v)[(size_t)row*64 + lane];
  float ss = x.x*x.x + x.y*x.y + x.z*x.z + x.w*x.w;
  #pragma unroll
  for (int m = 1; m < 64; m <<= 1) ss += __shfl_xor(ss, m, 64);
  float sc = 1.f / (sqrtf(ss) + 1e-4f);
  u16x4 o;
  o[0] = f2bf(x.x*sc); o[1] = f2bf(x.y*sc); o[2] = f2bf(x.z*sc); o[3] = f2bf(x.w*sc);
  *(u16x4*)(ob + (size_t)row*NE + lane*4) = o;
}

// ---------------- s_out = normalize(s_int + z[z_ind]) -> bf16 ----------------
__global__ __launch_bounds__(256) void build_sout_kernel(
    const float* __restrict__ s_int, const float* __restrict__ z,
    const int* __restrict__ z_ind, unsigned short* __restrict__ ob)
{
  const int row = blockIdx.x*4 + (threadIdx.x >> 6);
  const int lane = threadIdx.x & 63;
  const int zi = z_ind[row];
  float4 a = *((const float4*)s_int + (size_t)row*64 + lane);
  float4 c = *((const float4*)z + (size_t)zi*64 + lane);
  float4 x = {a.x + c.x, a.y + c.y, a.z + c.z, a.w + c.w};
  float ss = x.x*x.x + x.y*x.y + x.z*x.z + x.w*x.w;
  #pragma unroll
  for (int m = 1; m < 64; m <<= 1) ss += __shfl_xor(ss, m, 64);
  float sc = 1.f / (sqrtf(ss) + 1e-4f);
  u16x4 o;
  o[0] = f2bf(x.x*sc); o[1] = f2bf(x.y*sc); o[2] = f2bf(x.z*sc); o[3] = f2bf(x.w*sc);
  *(u16x4*)(ob + (size_t)row*NE + lane*4) = o;
}

extern "C" void kernel_launch(void* const* d_in, const int* in_sizes, int n_in,
                              void* d_out, int out_size, void* d_ws, size_t ws_size,
                              hipStream_t stream)
{
  const int* s  = (const int*)d_in[0];
  const int* sp = (const int*)d_in[1];
  const float* w_embed = (const float*)d_in[2];
  const float* z = (const float*)d_in[21];
  const float* scale = (const float*)d_in[22];
  float* out = (float*)d_out;

  size_t off = 0;
  auto allocB = [&](size_t bytes) -> void* {
    void* p = (void*)((char*)d_ws + off);
    off += ((bytes + 255) & ~(size_t)255);
    return p;
  };
  unsigned short* w1mh  = (unsigned short*)allocB((size_t)W1M_N * 2);
  unsigned short* w1ml  = (unsigned short*)allocB((size_t)W1M_N * 2);
  unsigned short* w2mh  = (unsigned short*)allocB((size_t)W2M_N * 2);
  unsigned short* w2ml  = (unsigned short*)allocB((size_t)W2M_N * 2);
  float* zT             = (float*)allocB(ZT_N * 4);
  float* wnorm          = (float*)allocB(64 * 8 * 4);
  unsigned short* lwh   = (unsigned short*)allocB((size_t)LW_N * 2);
  unsigned short* lwl   = (unsigned short*)allocB((size_t)LW_N * 2);
  float* s_int          = (float*)allocB((size_t)NB * NE * 4);
  float* diff_int       = (float*)allocB((size_t)NB * NE * 4);
  float* sp_out         = (float*)allocB((size_t)NB * NE * 4);
  unsigned short* soutb = (unsigned short*)allocB((size_t)NB * NE * 2);
  unsigned short* spoutb= (unsigned short*)allocB((size_t)NB * NE * 2);
  int*   z_ind          = (int*)allocB(NB * 4);

  // act hi/lo (bf16) staged in d_out: 2048 rows x 16KB each = 32MB + 32MB.
  unsigned short* acth = (unsigned short*)d_out;
  unsigned short* actl = acth + (size_t)CHUNK * KACT;

  prep_kernel<<<PREP_TOTAL2/256, 256, 0, stream>>>(
      (const float*)d_in[3],  (const float*)d_in[9],  (const float*)d_in[15],
      (const float*)d_in[5],  (const float*)d_in[11], (const float*)d_in[17],
      z, w_embed, w1mh, w1ml, w2mh, w2ml, zT, wnorm);

  for (int phi = 0; phi < 3; ++phi) {
    const float* b1 = (const float*)d_in[4 + phi*6];
    const float* b2 = (const float*)d_in[6 + phi*6];
    const float* lw = (const float*)d_in[7 + phi*6];
    const float* lb = (const float*)d_in[8 + phi*6];
    float* outvec = (phi == 0) ? s_int : (phi == 1) ? diff_int : sp_out;

    // lw convert + outvec bias-prefill (atomic GEMM accumulates on top)
    prep_lw_kernel<<<LW_N/256, 256, 0, stream>>>(lw, lwh, lwl, phi == 1, outvec, lb);

    for (int b0 = 0; b0 < NB; b0 += CHUNK) {
      if (phi == 1)
        conv_phi_kernel<3><<<CHUNK, 256, 0, stream>>>(
            s, sp, wnorm, w1mh + phi*6144, w1ml + phi*6144, b1,
            w2mh + phi*(128*576), w2ml + phi*(128*576), b2,
            acth, actl, phi, b0);
      else
        conv_phi_kernel<2><<<CHUNK, 256, 0, stream>>>(
            s, sp, wnorm, w1mh + phi*6144, w1ml + phi*6144, b1,
            w2mh + phi*(128*576), w2ml + phi*(128*576), b2,
            acth, actl, phi, b0);
      dim3 g(CHUNK/128, NE/64, KSPLIT);
      if (phi == 1)
        gemm_lds_tn<3><<<g, 256, 0, stream>>>(acth, actl, lwh, lwl,
            KACT, nullptr, outvec + (size_t)b0*NE, nullptr, nullptr);
      else
        gemm_lds_tn<1><<<g, 256, 0, stream>>>(acth, nullptr, lwh, nullptr,
            KACT, nullptr, outvec + (size_t)b0*NE, nullptr, nullptr);
    }
  }

  norm_to_bf16_kernel<<<NB/4, 256, 0, stream>>>(sp_out, spoutb);
  quant_kernel<<<NB/8, 256, 0, stream>>>(diff_int, zT, z_ind);
  build_sout_kernel<<<NB/4, 256, 0, stream>>>(s_int, z, z_ind, soutb);

  dim3 gg(NB/128, NB/64, 1);
  gemm_lds_tn<1><<<gg, 256, 0, stream>>>(soutb, nullptr, spoutb, nullptr,
      NE, out, nullptr, nullptr, scale);
}

// Round 11
// 522.469 us; speedup vs baseline: 1.0805x; 1.0805x over previous
//
#include <hip/hip_runtime.h>
#include <hip/hip_bf16.h>
#include <math.h>

#define NB 4096
#define SE 8
#define ND 64      // DICT
#define C1 64
#define C2 128
#define NE 256
#define NZ 1024
#define CHUNK 2048
#define KACT 8192
#define KSPLIT 8

#define W1M_N (3*12*64*8)        // 18432 (bf16 hi/lo, conv1 layout [j][o][c], j padded to 12)
#define W2M_N (3*18*128*32)      // 221184 (bf16 hi/lo, conv2 layout [j*2+h2][och][32])
#define ZT_N  (256*1024)
#define PREP_TOTAL (W1M_N + W2M_N + ZT_N)       // 501760
#define PREP_TOTAL2 (PREP_TOTAL + 512)          // +wnorm = 502272 = 1962*256
#define LW_N (NE*KACT)                          // 2097152 per phi

typedef __attribute__((ext_vector_type(8))) short bf16x8;
typedef __attribute__((ext_vector_type(4))) float f32x4;
typedef __attribute__((ext_vector_type(8))) unsigned short u16x8;
typedef __attribute__((ext_vector_type(4))) unsigned short u16x4;

static __device__ __forceinline__ unsigned short f2bf(float v) {
  __hip_bfloat16 h = __float2bfloat16(v);
  return __builtin_bit_cast(unsigned short, h);
}
static __device__ __forceinline__ float bf2f(unsigned short u) {
  return __bfloat162float(__builtin_bit_cast(__hip_bfloat16, u));
}

// ---------------- prep: w1 -> [j][o][c] bf16 hi/lo (j padded 9->12),
//     w2 -> [j*2+h2][och][32] bf16 hi/lo (coalesced per-step),
//     zT transpose, wnorm = max_norm-renormalized embedding table ----------------
__global__ __launch_bounds__(256) void prep_kernel(
    const float* __restrict__ w1_0, const float* __restrict__ w1_1, const float* __restrict__ w1_2,
    const float* __restrict__ w2_0, const float* __restrict__ w2_1, const float* __restrict__ w2_2,
    const float* __restrict__ z, const float* __restrict__ w_embed,
    unsigned short* __restrict__ w1mh, unsigned short* __restrict__ w1ml,
    unsigned short* __restrict__ w2mh, unsigned short* __restrict__ w2ml,
    float* __restrict__ zT, float* __restrict__ wnorm)
{
  int idx = blockIdx.x * 256 + threadIdx.x;
  if (idx < W1M_N) {
    int p = idx / 6144; int r = idx - p*6144;
    int j = r >> 9; int rem = r & 511; int o = rem >> 3; int c = rem & 7;
    const float* w1 = (p == 0) ? w1_0 : (p == 1) ? w1_1 : w1_2;
    // src layout [o][c][ky][kx]; dst [j][o*8 + c], j = ky*3+kx, j>=9 zero-padded
    float v = (j < 9) ? w1[o*72 + c*9 + j] : 0.f;
    unsigned short h = f2bf(v);
    w1mh[idx] = h;
    w1ml[idx] = f2bf(v - bf2f(h));
  } else if (idx < W1M_N + W2M_N) {
    int r0 = idx - W1M_N;
    int p = r0 / (128*576); int r = r0 - p*(128*576);
    int o = r / 576; int rem = r - o*576; int j = rem >> 6; int c = rem & 63;
    const float* w2 = (p == 0) ? w2_0 : (p == 1) ? w2_1 : w2_2;
    // w2 src [o][c][ky][kx] -> dst [p][(j*2 + c/32)*4096 + o*32 + (c%32)]
    float v = w2[o*576 + c*9 + j];
    unsigned short h = f2bf(v);
    const int d = p*(128*576) + ((j << 1) + (c >> 5))*4096 + o*32 + (c & 31);
    w2mh[d] = h;
    w2ml[d] = f2bf(v - bf2f(h));
  } else if (idx < PREP_TOTAL) {
    int r = idx - (W1M_N + W2M_N);
    int e = r >> 10, n = r & 1023;
    zT[r] = z[n*256 + e];   // zT[e][n]
  } else if (idx < PREP_TOTAL2) {
    int t = idx - PREP_TOTAL;           // 512 threads: o = t>>3, c = t&7
    int o = t >> 3, c = t & 7;
    float ss = 0.f;
    #pragma unroll
    for (int e = 0; e < 8; ++e) { float u = w_embed[o*8 + e]; ss += u*u; }
    float nrm = sqrtf(ss);
    float sc = fminf(1.f, 1.f / fmaxf(nrm, 1e-7f));
    wnorm[o*8 + c] = w_embed[o*8 + c] * sc;
  }
}

// ---------------- per-phi: lw -> bf16 hi (+ lo for phi2's bf16x3 path) ----------------
__global__ __launch_bounds__(256) void prep_lw_kernel(
    const float* __restrict__ lw, unsigned short* __restrict__ lwh,
    unsigned short* __restrict__ lwl, int do_lo)
{
  int idx = blockIdx.x * 256 + threadIdx.x;
  float v = lw[idx];
  unsigned short h = f2bf(v);
  lwh[idx] = h;
  if (do_lo) lwl[idx] = f2bf(v - bf2f(h));
}

// ---------------- fused embed + conv1(16x16 bf16x3 MFMA) + conv2(16x16 bf16 MFMA) ----
// 256 threads = 4 waves, 1 image/block, ~34.6KB LDS -> 4 blocks/CU (16 waves/CU).
// Embed: no LDS table -- pixels gather 32B rows of prep'd wnorm (global, L1-hot).
// c1 LDS cb-major c1[ch>>3][lin][ch&7]: b128 reads already bank-staggered
// (stride 1920B == 60 dw; cbk*60 mod 32 distinct per lk4 group -- R10 pad probe
// proved conflicts are off the critical path here).
// conv1 swapped 16x16: A=w1[out][k], B=x[k][px]; wave = 16-px quarter, 64 out-ch.
// conv2 (R6 decomposition -- empirical optimum of the mapped design space):
//   wave wid -> och [wid*32,+32), all 64 px (mf=4, nf=2): B-loads 2/step/wave
//   (1KB contiguous, L1-hot), A 8 ds_reads/step feeding 16 MFMAs, 8 acc chains.
// PASSES: 2 = Ah.Bh + Al.Bh ; 3 = + Ah.Bl. conv1 always 3-pass.
template<int PASSES>
__global__ __launch_bounds__(256, 4) void conv_phi_kernel(
    const int* __restrict__ s, const int* __restrict__ sp,
    const float* __restrict__ wnorm,
    const unsigned short* __restrict__ w1mh, const unsigned short* __restrict__ w1ml,
    const float* __restrict__ b1,
    const unsigned short* __restrict__ w2mh, const unsigned short* __restrict__ w2ml,
    const float* __restrict__ b2,
    unsigned short* __restrict__ acth, unsigned short* __restrict__ actl,
    int mode, int b_start)
{
  __shared__ __align__(16) unsigned short xph[960];    // [10][12][8] NHWC hi
  __shared__ __align__(16) unsigned short xpl[960];    // [10][12][8] NHWC lo
  __shared__ __align__(16) unsigned short c1h[7680];   // [8 cb][120 lin][8 sub]
  __shared__ __align__(16) unsigned short c1l[7680];

  const int tid = threadIdx.x;
  const int b = b_start + blockIdx.x;

  {
    int4 z4 = {0,0,0,0};
    for (int t = tid; t < 120; t += 256) { ((int4*)xph)[t] = z4; ((int4*)xpl)[t] = z4; }
    for (int t = tid; t < 960; t += 256) { ((int4*)c1h)[t] = z4; ((int4*)c1l)[t] = z4; }
  }
  __syncthreads();

  // build padded input tile: one pixel per thread, gather 32B wnorm rows from L1
  if (tid < 64) {
    const int si  = s[b*64 + tid];
    const int spi = sp[b*64 + tid];
    const float4 a0 = *(const float4*)(wnorm + si*8);
    const float4 a1v = *(const float4*)(wnorm + si*8 + 4);
    const float4 c0 = *(const float4*)(wnorm + spi*8);
    const float4 c1v = *(const float4*)(wnorm + spi*8 + 4);
    float e0[8] = {a0.x,a0.y,a0.z,a0.w, a1v.x,a1v.y,a1v.z,a1v.w};
    float e1[8] = {c0.x,c0.y,c0.z,c0.w, c1v.x,c1v.y,c1v.z,c1v.w};
    u16x8 hv, lv;
    #pragma unroll
    for (int c = 0; c < SE; ++c) {
      float v = (mode == 0) ? e0[c] : (mode == 1) ? (e1[c] - e0[c]) : e1[c];
      unsigned short h = f2bf(v);
      hv[c] = h;
      lv[c] = f2bf(v - bf2f(h));
    }
    const int lin = ((tid >> 3) + 1)*12 + (tid & 7) + 1;
    *(u16x8*)(xph + lin*8) = hv;
    *(u16x8*)(xpl + lin*8) = lv;
  }
  __syncthreads();

  // ---- conv1 via 16x16 MFMA (swapped): A=w1[out][k], B=x[k][pixel] ----
  {
    const int lane = tid & 63, wid = tid >> 6;
    const int ph = wid;
    const int l15 = lane & 15, lk4 = lane >> 4;

    f32x4 a1[4];
    #pragma unroll
    for (int fm = 0; fm < 4; ++fm) a1[fm] = (f32x4){0.f,0.f,0.f,0.f};

    #pragma unroll
    for (int kk = 0; kk < 3; ++kk) {
      const int j = (kk << 2) + lk4;          // 0..11; j>=9 rows are zero in w1m
      const int jc = (j > 8) ? 8 : j;         // clamp X read in-bounds (W=0 kills it)
      const int dy = jc / 3, dx = jc - 3*(jc/3);
      bf16x8 Wh[4], Wl[4];
      #pragma unroll
      for (int fm = 0; fm < 4; ++fm) {
        const int o = (fm << 4) + l15;
        Wh[fm] = *(const bf16x8*)(w1mh + (j << 9) + (o << 3));
        Wl[fm] = *(const bf16x8*)(w1ml + (j << 9) + (o << 3));
      }
      const int p = (ph << 4) + l15;
      const int lin = ((p >> 3) + dy)*12 + (p & 7) + dx;
      const bf16x8 Xh = *(const bf16x8*)(xph + (lin << 3));
      const bf16x8 Xl = *(const bf16x8*)(xpl + (lin << 3));
      __builtin_amdgcn_s_setprio(1);
      #pragma unroll
      for (int fm = 0; fm < 4; ++fm) {
        a1[fm] = __builtin_amdgcn_mfma_f32_16x16x32_bf16(Wh[fm], Xh, a1[fm], 0, 0, 0);
        a1[fm] = __builtin_amdgcn_mfma_f32_16x16x32_bf16(Wl[fm], Xh, a1[fm], 0, 0, 0);
        a1[fm] = __builtin_amdgcn_mfma_f32_16x16x32_bf16(Wh[fm], Xl, a1[fm], 0, 0, 0);
      }
      __builtin_amdgcn_s_setprio(0);
    }

    // c1 write (cb-major): lane holds out-ch obase..+3 of pixel p -> one u16x4
    const int p = (ph << 4) + l15;
    const int lin = ((p >> 3) + 1)*12 + (p & 7) + 1;
    #pragma unroll
    for (int fm = 0; fm < 4; ++fm) {
      const int obase = (fm << 4) + (lk4 << 2);
      const float4 bv = *(const float4*)(b1 + obase);
      const int idx2 = (obase >> 3)*960 + lin*8 + (obase & 7);
      u16x4 hv, lv;
      {
        float v0 = fmaxf(a1[fm][0] + bv.x, 0.f);
        float v1 = fmaxf(a1[fm][1] + bv.y, 0.f);
        float v2 = fmaxf(a1[fm][2] + bv.z, 0.f);
        float v3 = fmaxf(a1[fm][3] + bv.w, 0.f);
        hv[0] = f2bf(v0); hv[1] = f2bf(v1); hv[2] = f2bf(v2); hv[3] = f2bf(v3);
        lv[0] = f2bf(v0 - bf2f(hv[0])); lv[1] = f2bf(v1 - bf2f(hv[1]));
        lv[2] = f2bf(v2 - bf2f(hv[2])); lv[3] = f2bf(v3 - bf2f(hv[3]));
      }
      *(u16x4*)(c1h + idx2) = hv;
      *(u16x4*)(c1l + idx2) = lv;
    }
  }
  __syncthreads();

  // ---- conv2 MFMA: wave wid -> out-ch [wid*32,+32), M=64 px, K=576, barrier-free ----
  {
    const int lane = tid & 63, wid = tid >> 6;
    const int ob = wid << 5;
    const int l15 = lane & 15, lk4 = lane >> 4;
    const int y0b = l15 >> 3, x0 = l15 & 7;

    f32x4 acc[4][2];
    #pragma unroll
    for (int mf = 0; mf < 4; ++mf)
      #pragma unroll
      for (int nf = 0; nf < 2; ++nf) acc[mf][nf] = (f32x4){0.f,0.f,0.f,0.f};

    #pragma unroll
    for (int j = 0; j < 9; ++j) {
      const int dy = j / 3, dx = j - 3*(j/3);
      #pragma unroll
      for (int h2 = 0; h2 < 2; ++h2) {
        const int sbase = ((j << 1) + h2) << 12;       // step-slice [j*2+h2][128][32]
        bf16x8 Bh[2], Bl[2];
        #pragma unroll
        for (int nf = 0; nf < 2; ++nf) {
          const int orow = ob + (nf << 4) + l15;
          const int a = sbase + orow*32 + (lk4 << 3);  // 1KB contiguous per wave
          Bh[nf] = *(const bf16x8*)(w2mh + a);
          if (PASSES == 3) Bl[nf] = *(const bf16x8*)(w2ml + a);
        }
        const int cbk = (h2 << 2) + lk4;
        bf16x8 Ah[4], Al[4];
        #pragma unroll
        for (int mf = 0; mf < 4; ++mf) {
          const int lin = ((mf << 1) + y0b + dy)*12 + x0 + dx;
          const int a = cbk*960 + (lin << 3);
          Ah[mf] = *(const bf16x8*)(c1h + a);
          Al[mf] = *(const bf16x8*)(c1l + a);
        }
        __builtin_amdgcn_s_setprio(1);
        #pragma unroll
        for (int mf = 0; mf < 4; ++mf) {
          #pragma unroll
          for (int nf = 0; nf < 2; ++nf) {
            acc[mf][nf] = __builtin_amdgcn_mfma_f32_16x16x32_bf16(Ah[mf], Bh[nf], acc[mf][nf], 0, 0, 0);
            acc[mf][nf] = __builtin_amdgcn_mfma_f32_16x16x32_bf16(Al[mf], Bh[nf], acc[mf][nf], 0, 0, 0);
            if (PASSES == 3)
              acc[mf][nf] = __builtin_amdgcn_mfma_f32_16x16x32_bf16(Ah[mf], Bl[nf], acc[mf][nf], 0, 0, 0);
          }
        }
        __builtin_amdgcn_s_setprio(0);
      }
    }

    // store act[img][o*64 + pixel] as bf16 hi (+ lo for PASSES==3)
    const size_t rowbase = (size_t)blockIdx.x * 8192;
    #pragma unroll
    for (int nf = 0; nf < 2; ++nf) {
      const int col = ob + (nf << 4) + l15;
      const float bv = b2[col];
      #pragma unroll
      for (int mf = 0; mf < 4; ++mf) {
        const int p0 = mf*16 + lk4*4;
        u16x4 hv, lv;
        #pragma unroll
        for (int r2 = 0; r2 < 4; ++r2) {
          float v = fmaxf(acc[mf][nf][r2] + bv, 0.f);
          unsigned short hq = f2bf(v);
          hv[r2] = hq;
          lv[r2] = f2bf(v - bf2f(hq));
        }
        *(u16x4*)(acth + rowbase + col*64 + p0) = hv;
        if (PASSES == 3)
          *(u16x4*)(actl + rowbase + col*64 + p0) = lv;
      }
    }
  }
}

// ---------------- LDS-staged bf16 MFMA TN GEMM ----------------
// BM=128, BN=64, BK=64. 256 thr = 4 waves (2x2): wave owns 64x32 = 4x2 frags 16x16.
// A[M][K], B[N][K] bf16 row-major. PASSES: 1 = Ah.Bh ; 3 = Ah.Bh + Ah.Bl + Al.Bh.
// XOR-swizzled LDS (elem col8 ^ ((row&7)<<3)) -> conflict-free ds_read_b128 (T2).
// KC = K/gridDim.z; Cpart[z][M][N] partials, or Cdirect with bias/scale.
template<int PASSES>
__global__ __launch_bounds__(256) void gemm_lds_tn(
    const unsigned short* __restrict__ Ahp, const unsigned short* __restrict__ Alp,
    const unsigned short* __restrict__ Bhp, const unsigned short* __restrict__ Blp,
    int K, float* __restrict__ Cdirect, float* __restrict__ Cpart,
    const float* __restrict__ bias, const float* __restrict__ scale_ptr)
{
  constexpr int NOP = (PASSES == 3) ? 2 : 1;
  __shared__ __align__(16) unsigned short As[NOP][128*64];
  __shared__ __align__(16) unsigned short Bs[NOP][64*64];

  const int tid = threadIdx.x;
  const int lane = tid & 63, wid = tid >> 6;
  const int wm = wid >> 1, wn = wid & 1;
  const int l15 = lane & 15, lk4 = lane >> 4;
  const int M = gridDim.x << 7, N = gridDim.y << 6;
  const int KC = K / gridDim.z;
  const int bm = blockIdx.x << 7, bn = blockIdx.y << 6;
  const int kbase = blockIdx.z * KC;
  const int NT = KC >> 6;

  const int sr = tid >> 3;          // staging row group 0..31
  const int sc8 = (tid & 7) * 8;    // k-elem chunk (16B) within BK=64

  const unsigned short* gA[NOP];
  const unsigned short* gB[NOP];
  gA[0] = Ahp; gB[0] = Bhp;
  if (PASSES == 3) { gA[1] = Alp; gB[1] = Blp; }

  u16x8 ra[NOP][4], rb[NOP][2];

  f32x4 acc[4][2];
  #pragma unroll
  for (int fm = 0; fm < 4; ++fm)
    #pragma unroll
    for (int nf = 0; nf < 2; ++nf) acc[fm][nf] = (f32x4){0.f,0.f,0.f,0.f};

  // prologue: load tile 0 into regs
  {
    const int k0 = kbase + sc8;
    #pragma unroll
    for (int p = 0; p < NOP; ++p) {
      #pragma unroll
      for (int i = 0; i < 4; ++i)
        ra[p][i] = *(const u16x8*)(gA[p] + (size_t)(bm + sr + i*32) * K + k0);
      #pragma unroll
      for (int i = 0; i < 2; ++i)
        rb[p][i] = *(const u16x8*)(gB[p] + (size_t)(bn + sr + i*32) * K + k0);
    }
  }

  for (int t = 0; t < NT; ++t) {
    __syncthreads();                 // LDS consumers of previous tile done
    // swizzled ds_write of staged regs
    #pragma unroll
    for (int p = 0; p < NOP; ++p) {
      #pragma unroll
      for (int i = 0; i < 4; ++i) {
        const int r = sr + i*32;
        *(u16x8*)(&As[p][r*64 + (sc8 ^ ((r & 7) << 3))]) = ra[p][i];
      }
      #pragma unroll
      for (int i = 0; i < 2; ++i) {
        const int r = sr + i*32;
        *(u16x8*)(&Bs[p][r*64 + (sc8 ^ ((r & 7) << 3))]) = rb[p][i];
      }
    }
    __syncthreads();                 // LDS tile ready
    if (t + 1 < NT) {                // issue next tile's global loads early (T14)
      const int k0 = kbase + ((t + 1) << 6) + sc8;
      #pragma unroll
      for (int p = 0; p < NOP; ++p) {
        #pragma unroll
        for (int i = 0; i < 4; ++i)
          ra[p][i] = *(const u16x8*)(gA[p] + (size_t)(bm + sr + i*32) * K + k0);
        #pragma unroll
        for (int i = 0; i < 2; ++i)
          rb[p][i] = *(const u16x8*)(gB[p] + (size_t)(bn + sr + i*32) * K + k0);
      }
    }
    // compute current tile (hides the loads above)
    #pragma unroll
    for (int ks = 0; ks < 2; ++ks) {
      const int kb = ks*32 + lk4*8;
      bf16x8 af[NOP][4], bf[NOP][2];
      #pragma unroll
      for (int p = 0; p < NOP; ++p) {
        #pragma unroll
        for (int fm = 0; fm < 4; ++fm) {
          const int r = wm*64 + fm*16 + l15;
          af[p][fm] = *(const bf16x8*)(&As[p][r*64 + (kb ^ ((r & 7) << 3))]);
        }
        #pragma unroll
        for (int nf = 0; nf < 2; ++nf) {
          const int r = wn*32 + nf*16 + l15;
          bf[p][nf] = *(const bf16x8*)(&Bs[p][r*64 + (kb ^ ((r & 7) << 3))]);
        }
      }
      #pragma unroll
      for (int fm = 0; fm < 4; ++fm) {
        #pragma unroll
        for (int nf = 0; nf < 2; ++nf) {
          acc[fm][nf] = __builtin_amdgcn_mfma_f32_16x16x32_bf16(af[0][fm], bf[0][nf], acc[fm][nf], 0, 0, 0);
          if (PASSES == 3) {
            acc[fm][nf] = __builtin_amdgcn_mfma_f32_16x16x32_bf16(af[0][fm], bf[1][nf], acc[fm][nf], 0, 0, 0);
            acc[fm][nf] = __builtin_amdgcn_mfma_f32_16x16x32_bf16(af[1][fm], bf[0][nf], acc[fm][nf], 0, 0, 0);
          }
        }
      }
    }
  }

  // epilogue: C layout col=l15, row=lk4*4+r2
  if (Cpart) {
    float* base = Cpart + (size_t)blockIdx.z * ((size_t)M * N);
    #pragma unroll
    for (int fm = 0; fm < 4; ++fm) {
      #pragma unroll
      for (int nf = 0; nf < 2; ++nf) {
        const int row0 = bm + wm*64 + fm*16 + lk4*4;
        const int col  = bn + wn*32 + nf*16 + l15;
        #pragma unroll
        for (int r2 = 0; r2 < 4; ++r2)
          base[(size_t)(row0 + r2) * N + col] = acc[fm][nf][r2];
      }
    }
  } else {
    float alpha = scale_ptr ? expf(scale_ptr[0]) : 1.f;
    #pragma unroll
    for (int fm = 0; fm < 4; ++fm) {
      #pragma unroll
      for (int nf = 0; nf < 2; ++nf) {
        const int row0 = bm + wm*64 + fm*16 + lk4*4;
        const int col  = bn + wn*32 + nf*16 + l15;
        const float bv = bias ? bias[col] : 0.f;
        #pragma unroll
        for (int r2 = 0; r2 < 4; ++r2)
          Cdirect[(size_t)(row0 + r2) * N + col] = alpha * acc[fm][nf][r2] + bv;
      }
    }
  }
}

// ---------------- split-K reduce + bias ----------------
__global__ __launch_bounds__(256) void reduce_bias_kernel(
    const float* __restrict__ part, const float* __restrict__ bias, float* __restrict__ out)
{
  const int idx = blockIdx.x * 256 + threadIdx.x;
  float a = bias[idx & (NE-1)];
  #pragma unroll
  for (int q = 0; q < KSPLIT; ++q) a += part[(size_t)q * (CHUNK*NE) + idx];
  out[idx] = a;
}

// ---------------- cdist + argmax (farthest code), 8 batch rows per block ----------------
__global__ __launch_bounds__(256) void quant_kernel(
    const float* __restrict__ diff, const float* __restrict__ zT, int* __restrict__ z_ind)
{
  __shared__ __align__(16) float d[8][NE];
  __shared__ float wv[8][4];
  __shared__ int wni[8][4];
  const int tid = threadIdx.x;
  const int b0 = blockIdx.x * 8;
  for (int j = tid; j < 8*NE; j += 256) (&d[0][0])[j] = diff[(size_t)b0*NE + j];
  __syncthreads();

  float zz[4] = {0.f, 0.f, 0.f, 0.f};
  float dot[8][4] = {};
  for (int e = 0; e < NE; e += 4) {
    float4 dd[8];
    #pragma unroll
    for (int r = 0; r < 8; ++r) dd[r] = *(const float4*)(&d[r][e]);
    #pragma unroll
    for (int u = 0; u < 4; ++u) {
      const float* zr = zT + (size_t)(e + u) * NZ + tid;
      float z0 = zr[0], z1 = zr[256], z2 = zr[512], z3 = zr[768];
      zz[0] = fmaf(z0, z0, zz[0]); zz[1] = fmaf(z1, z1, zz[1]);
      zz[2] = fmaf(z2, z2, zz[2]); zz[3] = fmaf(z3, z3, zz[3]);
      #pragma unroll
      for (int r = 0; r < 8; ++r) {
        const float de = (u == 0) ? dd[r].x : (u == 1) ? dd[r].y : (u == 2) ? dd[r].z : dd[r].w;
        dot[r][0] = fmaf(z0, de, dot[r][0]);
        dot[r][1] = fmaf(z1, de, dot[r][1]);
        dot[r][2] = fmaf(z2, de, dot[r][2]);
        dot[r][3] = fmaf(z3, de, dot[r][3]);
      }
    }
  }

  const int lane = tid & 63, wid = tid >> 6;
  #pragma unroll
  for (int r = 0; r < 8; ++r) {
    float best = zz[0] - 2.f*dot[r][0]; int bi = tid;
    float v1 = zz[1] - 2.f*dot[r][1]; if (v1 > best) { best = v1; bi = tid + 256; }
    float v2 = zz[2] - 2.f*dot[r][2]; if (v2 > best) { best = v2; bi = tid + 512; }
    float v3 = zz[3] - 2.f*dot[r][3]; if (v3 > best) { best = v3; bi = tid + 768; }
    for (int m = 1; m < 64; m <<= 1) {
      float ov = __shfl_xor(best, m, 64);
      int   oi = __shfl_xor(bi, m, 64);
      if (ov > best || (ov == best && oi < bi)) { best = ov; bi = oi; }
    }
    if (lane == 0) { wv[r][wid] = best; wni[r][wid] = bi; }
  }
  __syncthreads();
  if (tid < 8) {
    float best = wv[tid][0]; int bi = wni[tid][0];
    #pragma unroll
    for (int w = 1; w < 4; ++w) {
      float v = wv[tid][w]; int n = wni[tid][w];
      if (v > best || (v == best && n < bi)) { best = v; bi = n; }
    }
    z_ind[b0 + tid] = bi;
  }
}

// ---------------- normalize fp32 rows -> bf16 rows ----------------
__global__ __launch_bounds__(256) void norm_to_bf16_kernel(
    const float* __restrict__ v, unsigned short* __restrict__ ob)
{
  const int row = blockIdx.x*4 + (threadIdx.x >> 6);
  const int lane = threadIdx.x & 63;
  float4 x = ((const float4*)v)[(size_t)row*64 + lane];
  float ss = x.x*x.x + x.y*x.y + x.z*x.z + x.w*x.w;
  #pragma unroll
  for (int m = 1; m < 64; m <<= 1) ss += __shfl_xor(ss, m, 64);
  float sc = 1.f / (sqrtf(ss) + 1e-4f);
  u16x4 o;
  o[0] = f2bf(x.x*sc); o[1] = f2bf(x.y*sc); o[2] = f2bf(x.z*sc); o[3] = f2bf(x.w*sc);
  *(u16x4*)(ob + (size_t)row*NE + lane*4) = o;
}

// ---------------- s_out = normalize(s_int + z[z_ind]) -> bf16 ----------------
__global__ __launch_bounds__(256) void build_sout_kernel(
    const float* __restrict__ s_int, const float* __restrict__ z,
    const int* __restrict__ z_ind, unsigned short* __restrict__ ob)
{
  const int row = blockIdx.x*4 + (threadIdx.x >> 6);
  const int lane = threadIdx.x & 63;
  const int zi = z_ind[row];
  float4 a = *((const float4*)s_int + (size_t)row*64 + lane);
  float4 c = *((const float4*)z + (size_t)zi*64 + lane);
  float4 x = {a.x + c.x, a.y + c.y, a.z + c.z, a.w + c.w};
  float ss = x.x*x.x + x.y*x.y + x.z*x.z + x.w*x.w;
  #pragma unroll
  for (int m = 1; m < 64; m <<= 1) ss += __shfl_xor(ss, m, 64);
  float sc = 1.f / (sqrtf(ss) + 1e-4f);
  u16x4 o;
  o[0] = f2bf(x.x*sc); o[1] = f2bf(x.y*sc); o[2] = f2bf(x.z*sc); o[3] = f2bf(x.w*sc);
  *(u16x4*)(ob + (size_t)row*NE + lane*4) = o;
}

extern "C" void kernel_launch(void* const* d_in, const int* in_sizes, int n_in,
                              void* d_out, int out_size, void* d_ws, size_t ws_size,
                              hipStream_t stream)
{
  const int* s  = (const int*)d_in[0];
  const int* sp = (const int*)d_in[1];
  const float* w_embed = (const float*)d_in[2];
  const float* z = (const float*)d_in[21];
  const float* scale = (const float*)d_in[22];
  float* out = (float*)d_out;

  size_t off = 0;
  auto allocB = [&](size_t bytes) -> void* {
    void* p = (void*)((char*)d_ws + off);
    off += ((bytes + 255) & ~(size_t)255);
    return p;
  };
  unsigned short* w1mh  = (unsigned short*)allocB((size_t)W1M_N * 2);
  unsigned short* w1ml  = (unsigned short*)allocB((size_t)W1M_N * 2);
  unsigned short* w2mh  = (unsigned short*)allocB((size_t)W2M_N * 2);
  unsigned short* w2ml  = (unsigned short*)allocB((size_t)W2M_N * 2);
  float* zT             = (float*)allocB(ZT_N * 4);
  float* wnorm          = (float*)allocB(64 * 8 * 4);
  unsigned short* lwh   = (unsigned short*)allocB((size_t)LW_N * 2);
  unsigned short* lwl   = (unsigned short*)allocB((size_t)LW_N * 2);
  float* s_int          = (float*)allocB((size_t)NB * NE * 4);
  float* diff_int       = (float*)allocB((size_t)NB * NE * 4);
  float* sp_out         = (float*)allocB((size_t)NB * NE * 4);
  unsigned short* soutb = (unsigned short*)allocB((size_t)NB * NE * 2);
  unsigned short* spoutb= (unsigned short*)allocB((size_t)NB * NE * 2);
  int*   z_ind          = (int*)allocB(NB * 4);
  float* part           = (float*)allocB((size_t)CHUNK * NE * KSPLIT * 4);  // ~16.8 MB

  // act hi/lo (bf16) staged in d_out: 2048 rows x 16KB each = 32MB + 32MB.
  unsigned short* acth = (unsigned short*)d_out;
  unsigned short* actl = acth + (size_t)CHUNK * KACT;

  prep_kernel<<<PREP_TOTAL2/256, 256, 0, stream>>>(
      (const float*)d_in[3],  (const float*)d_in[9],  (const float*)d_in[15],
      (const float*)d_in[5],  (const float*)d_in[11], (const float*)d_in[17],
      z, w_embed, w1mh, w1ml, w2mh, w2ml, zT, wnorm);

  for (int phi = 0; phi < 3; ++phi) {
    const float* b1 = (const float*)d_in[4 + phi*6];
    const float* b2 = (const float*)d_in[6 + phi*6];
    const float* lw = (const float*)d_in[7 + phi*6];
    const float* lb = (const float*)d_in[8 + phi*6];
    float* outvec = (phi == 0) ? s_int : (phi == 1) ? diff_int : sp_out;

    prep_lw_kernel<<<LW_N/256, 256, 0, stream>>>(lw, lwh, lwl, phi == 1);

    for (int b0 = 0; b0 < NB; b0 += CHUNK) {
      if (phi == 1)
        conv_phi_kernel<3><<<CHUNK, 256, 0, stream>>>(
            s, sp, wnorm, w1mh + phi*6144, w1ml + phi*6144, b1,
            w2mh + phi*(128*576), w2ml + phi*(128*576), b2,
            acth, actl, phi, b0);
      else
        conv_phi_kernel<2><<<CHUNK, 256, 0, stream>>>(
            s, sp, wnorm, w1mh + phi*6144, w1ml + phi*6144, b1,
            w2mh + phi*(128*576), w2ml + phi*(128*576), b2,
            acth, actl, phi, b0);
      dim3 g(CHUNK/128, NE/64, KSPLIT);
      if (phi == 1)
        gemm_lds_tn<3><<<g, 256, 0, stream>>>(acth, actl, lwh, lwl,
            KACT, nullptr, part, nullptr, nullptr);
      else
        gemm_lds_tn<1><<<g, 256, 0, stream>>>(acth, nullptr, lwh, nullptr,
            KACT, nullptr, part, nullptr, nullptr);
      reduce_bias_kernel<<<(CHUNK*NE)/256, 256, 0, stream>>>(part, lb, outvec + (size_t)b0*NE);
    }
  }

  norm_to_bf16_kernel<<<NB/4, 256, 0, stream>>>(sp_out, spoutb);
  quant_kernel<<<NB/8, 256, 0, stream>>>(diff_int, zT, z_ind);
  build_sout_kernel<<<NB/4, 256, 0, stream>>>(s_int, z, z_ind, soutb);

  dim3 gg(NB/128, NB/64, 1);
  gemm_lds_tn<1><<<gg, 256, 0, stream>>>(soutb, nullptr, spoutb, nullptr,
      NE, out, nullptr, nullptr, scale);
}